// Round 11
// baseline (223.736 us; speedup 1.0000x reference)
//
#include <hip/hip_runtime.h>
#include <math.h>

#define S_  2048
#define D_  768
#define H_  12

typedef float f32x4 __attribute__((ext_vector_type(4)));
typedef __bf16 bf16x8 __attribute__((ext_vector_type(8)));
typedef unsigned short u16;

#define MFMA(a, b, c) __builtin_amdgcn_mfma_f32_16x16x32_bf16(a, b, c, 0, 0, 0)
#define LOG2E 1.44269504f

__device__ __forceinline__ u16 f2bf(float f) {
  union { float f; unsigned u; } c;
  c.f = f;
  unsigned r = c.u + 0x7FFFu + ((c.u >> 16) & 1u);
  return (u16)(r >> 16);
}

typedef const unsigned int __attribute__((address_space(1))) gu32;
typedef unsigned int __attribute__((address_space(3))) lu32;

// global -> LDS direct copy, 16 B per lane. LDS dest must be wave-uniform;
// HW writes lane l at dst + l*16. Global src is per-lane.
__device__ __forceinline__ void gload_lds16(const void* g, void* l) {
  __builtin_amdgcn_global_load_lds((gu32*)g, (lu32*)l, 16, 0, 0);
}

// ---------------------------------------------------------------------------
// RoPE trig table: trig[s*16 + p] = (cos, sin)(s * 10000^(-p/16))
// ---------------------------------------------------------------------------
__global__ __launch_bounds__(256) void trig_kernel(float2* __restrict__ trig) {
  int i = blockIdx.x * 256 + threadIdx.x;
  int s = i >> 4, p = i & 15;
  float inv = powf(10000.0f, -(float)p / 16.0f);
  float f = (float)s * inv;
  trig[i] = make_float2(cosf(f), sinf(f));
}

// ---------------------------------------------------------------------------
// fp32 -> bf16 conversion of x and the 4 weight matrices (one launch).
// x: 3145728 elems (786432 float4), each W: 589824 elems (147456 float4).
// ---------------------------------------------------------------------------
__global__ __launch_bounds__(256) void cvt_all(
    const float* __restrict__ x, const float* __restrict__ wq,
    const float* __restrict__ wk, const float* __restrict__ wv,
    const float* __restrict__ wo, u16* __restrict__ xb, u16* __restrict__ wqb,
    u16* __restrict__ wkb, u16* __restrict__ wvb, u16* __restrict__ wob) {
  int idx = blockIdx.x * 256 + threadIdx.x;
  const float4* src;
  u16* dst;
  int off;
  if (idx < 786432) {
    src = (const float4*)x; dst = xb; off = idx;
  } else {
    int r = idx - 786432;
    int sel = r / 147456;
    off = r - sel * 147456;
    src = (const float4*)(sel == 0 ? wq : sel == 1 ? wk : sel == 2 ? wv : wo);
    dst = sel == 0 ? wqb : sel == 1 ? wkb : sel == 2 ? wvb : wob;
  }
  float4 v = src[off];
  ushort4 h = make_ushort4(f2bf(v.x), f2bf(v.y), f2bf(v.z), f2bf(v.w));
  *(ushort4*)(dst + (size_t)off * 4) = h;
}

// ---------------------------------------------------------------------------
// bf16 MFMA projection: out[m,n] = sum_k A[m,k] * W[n,k] + bias[n]
// M=4096, N=768, K=768. 64x64 tile, 4 waves (2x2), 16x16x32 MFMA.
// MODE 0: fp32 out[m*768+n] (final projection)
// MODE 1: RoPE + bf16 scatter to [b,h,s,64]     (q, k)
// MODE 3: bf16 transposed scatter to [b,h,64,s] (v)
// ---------------------------------------------------------------------------
template <int MODE>
__global__ __launch_bounds__(256) void proj_mfma(
    const u16* __restrict__ A, const u16* __restrict__ Wb,
    const float* __restrict__ bias, void* __restrict__ dst,
    const float2* __restrict__ trig) {
  __shared__ u16 As[4096];  // [64 m][64 k], XOR-swizzled 16B chunks
  __shared__ u16 Bs[4096];  // [64 n][64 k]
  const int t = threadIdx.x;
  const int l = t & 63, w = t >> 6;
  const int wr = w >> 1, wc = w & 1;
  const int n0 = blockIdx.x * 64;
  const int m0 = blockIdx.y * 64;

  const f32x4 zero = {0.f, 0.f, 0.f, 0.f};
  f32x4 acc[2][2];
#pragma unroll
  for (int i = 0; i < 2; ++i)
#pragma unroll
    for (int j = 0; j < 2; ++j) acc[i][j] = zero;

  for (int k0 = 0; k0 < 768; k0 += 64) {
    __syncthreads();  // previous iteration's frag reads complete
#pragma unroll
    for (int rnd = 0; rnd < 2; ++rnd) {
      int id = t + rnd * 256;
      int r = id >> 3, c = id & 7;
      int cs = ((c ^ (r & 7)) << 3);  // source pre-swizzle (rule #21)
      gload_lds16(A + (size_t)(m0 + r) * 768 + k0 + cs,
                  &As[(w * 64 + rnd * 256) * 8]);
      gload_lds16(Wb + (size_t)(n0 + r) * 768 + k0 + cs,
                  &Bs[(w * 64 + rnd * 256) * 8]);
    }
    __syncthreads();  // compiler drains vmcnt before barrier

    bf16x8 af[2][2], bw[2][2];
#pragma unroll
    for (int mf = 0; mf < 2; ++mf)
#pragma unroll
      for (int kh = 0; kh < 2; ++kh) {
        int row = wr * 32 + mf * 16 + (l & 15);
        int ch = (kh * 4 + (l >> 4)) ^ (row & 7);
        af[mf][kh] = *(const bf16x8*)&As[row * 64 + ch * 8];
      }
#pragma unroll
    for (int nf = 0; nf < 2; ++nf)
#pragma unroll
      for (int kh = 0; kh < 2; ++kh) {
        int row = wc * 32 + nf * 16 + (l & 15);
        int ch = (kh * 4 + (l >> 4)) ^ (row & 7);
        bw[nf][kh] = *(const bf16x8*)&Bs[row * 64 + ch * 8];
      }
#pragma unroll
    for (int kh = 0; kh < 2; ++kh)
#pragma unroll
      for (int mf = 0; mf < 2; ++mf)
#pragma unroll
        for (int nf = 0; nf < 2; ++nf)
          acc[mf][nf] = MFMA(af[mf][kh], bw[nf][kh], acc[mf][nf]);
  }

  // Epilogue. C layout: col = lane&15, row = (lane>>4)*4 + reg  [m89/m91]
  const int b_ = m0 >> 11;
  const int h = n0 >> 6;
#pragma unroll
  for (int mf = 0; mf < 2; ++mf) {
    const int rbase = m0 + wr * 32 + mf * 16 + ((l >> 4) << 2);
#pragma unroll
    for (int nf = 0; nf < 2; ++nf) {
      const int col = wc * 32 + nf * 16 + (l & 15);
      const int n = n0 + col;
      const float bia = bias[n];
      f32x4 v = acc[mf][nf];
      if (MODE == 0) {
        float* out = (float*)dst;
#pragma unroll
        for (int g = 0; g < 4; ++g)
          out[(size_t)(rbase + g) * 768 + n] = v[g] + bia;
      } else if (MODE == 1) {
        u16* o = (u16*)dst;
        const int d = col;  // n0 is 64-aligned -> d = col, h uniform
#pragma unroll
        for (int g = 0; g < 4; ++g) {
          float val = v[g] + bia;
          float partner = __shfl_xor(val, 1);  // paired d (d^1) value
          if (d < 32) {
            int s = (rbase + g) & (S_ - 1);
            float2 cs = trig[s * 16 + (d >> 1)];
            val = (d & 1) ? (val * cs.x + partner * cs.y)
                          : (val * cs.x - partner * cs.y);
          }
          o[((size_t)(b_ * H_ + h) * S_ + ((rbase + g) & (S_ - 1))) * 64 + d] =
              f2bf(val);
        }
      } else {  // MODE 3: V transposed [b,h,d,s]; 4 regs = 4 consecutive s
        u16* o = (u16*)dst;
        const int d = col;
        ushort4 pk;
        pk.x = f2bf(v[0] + bia);
        pk.y = f2bf(v[1] + bia);
        pk.z = f2bf(v[2] + bia);
        pk.w = f2bf(v[3] + bia);
        *(ushort4*)&o[((size_t)(b_ * H_ + h) * 64 + d) * S_ +
                      (rbase & (S_ - 1))] = pk;
      }
    }
  }
}

// ---------------------------------------------------------------------------
// bf16 MFMA causal flash attention. Block = (bh, 64 q-rows), 4 waves,
// wave w owns q-rows [w*16, w*16+16). K tile [64 k][64 d], Vt tile
// [64 d][64 k] (from transposed V), P tile [64 q][64 k] — all XOR-swizzled.
// ---------------------------------------------------------------------------
__global__ __launch_bounds__(256) void attn_mfma(
    const u16* __restrict__ qg, const u16* __restrict__ kg,
    const u16* __restrict__ vtg, u16* __restrict__ ctx) {
  __shared__ u16 Ks[4096];
  __shared__ u16 Vts[4096];
  __shared__ u16 Ps[4096];
  const int t = threadIdx.x, l = t & 63, w = t >> 6;

  // XCD-aware bijective remap (768 = 8*96): same-bh blocks share an XCD's L2;
  // within each bh, largest q-tile first (longest blocks start earliest).
  int orig = blockIdx.y * 32 + blockIdx.x;
  int logical = (orig & 7) * 96 + (orig >> 3);
  const int bh = logical >> 5;
  const int qt = 31 - (logical & 31);
  const int q0 = qt * 64;

  const u16* qp = qg + (size_t)bh * (S_ * 64);
  const u16* kp = kg + (size_t)bh * (S_ * 64);
  const u16* vp = vtg + (size_t)bh * (64 * S_);

  // Q fragments live in registers: A-layout row = l&15, k-chunk = (l>>4)*8
  bf16x8 aq[2];
  {
    const u16* qrow = qp + (size_t)(q0 + w * 16 + (l & 15)) * 64 + ((l >> 4) * 8);
    aq[0] = *(const bf16x8*)(qrow);
    aq[1] = *(const bf16x8*)(qrow + 32);
  }

  const f32x4 zero = {0.f, 0.f, 0.f, 0.f};
  f32x4 o[4];
  float m_r[4], l_r[4];
#pragma unroll
  for (int i = 0; i < 4; ++i) {
    o[i] = zero;
    m_r[i] = -3.0e38f;
    l_r[i] = 0.f;
  }

  for (int kt = 0; kt <= qt; ++kt) {
    const int k0 = kt * 64;
    __syncthreads();  // all waves done reading previous K/Vt
#pragma unroll
    for (int rnd = 0; rnd < 2; ++rnd) {
      int id = t + rnd * 256;
      int r = id >> 3, c = id & 7;
      int cs = ((c ^ (r & 7)) << 3);
      gload_lds16(kp + (size_t)(k0 + r) * 64 + cs, &Ks[(w * 64 + rnd * 256) * 8]);
      gload_lds16(vp + (size_t)r * S_ + k0 + cs, &Vts[(w * 64 + rnd * 256) * 8]);
    }
    __syncthreads();

    // S = Q K^T : D[q][kcol], 4 k-subtiles of 16
    f32x4 sacc[4];
#pragma unroll
    for (int ks = 0; ks < 4; ++ks) sacc[ks] = zero;
#pragma unroll
    for (int ks = 0; ks < 4; ++ks)
#pragma unroll
      for (int kh = 0; kh < 2; ++kh) {
        int row = ks * 16 + (l & 15);
        int ch = (kh * 4 + (l >> 4)) ^ (row & 7);
        bf16x8 bk = *(const bf16x8*)&Ks[row * 64 + ch * 8];
        sacc[ks] = MFMA(aq[kh], bk, sacc[ks]);
      }

    // online softmax, rows spread over 16-lane groups
    const int prow_b = w * 16 + ((l >> 4) << 2);
    const int qrow_b = q0 + prow_b;
#pragma unroll
    for (int g = 0; g < 4; ++g) {
      const int qrow = qrow_b + g;
      float sv[4], mx = -3.0e38f;
#pragma unroll
      for (int ks = 0; ks < 4; ++ks) {
        int kcol = k0 + ks * 16 + (l & 15);
        float xv = sacc[ks][g] * 0.125f;
        if (kcol > qrow) xv = -3.0e38f;  // causal mask
        sv[ks] = xv;
        mx = fmaxf(mx, xv);
      }
#pragma unroll
      for (int off = 1; off < 16; off <<= 1)
        mx = fmaxf(mx, __shfl_xor(mx, off));
      float mnew = fmaxf(m_r[g], mx);
      float corr = __expf(m_r[g] - mnew);
      m_r[g] = mnew;
      float rs = 0.f;
      const int prow = prow_b + g;
      const int swz = (prow & 7) << 4;
#pragma unroll
      for (int ks = 0; ks < 4; ++ks) {
        float p = __expf(sv[ks] - mnew);
        rs += p;
        int byt = (ks * 32 + ((l & 15) * 2)) ^ swz;
        Ps[prow * 64 + (byt >> 1)] = f2bf(p);  // wave-private rows: no barrier
      }
#pragma unroll
      for (int off = 1; off < 16; off <<= 1) rs += __shfl_xor(rs, off);
      l_r[g] = l_r[g] * corr + rs;
#pragma unroll
      for (int ds = 0; ds < 4; ++ds) o[ds][g] *= corr;
    }

    // O += P V : A = P[q][k] (LDS), B = V[k][d] via Vt rows
#pragma unroll
    for (int kh = 0; kh < 2; ++kh) {
      int prow = w * 16 + (l & 15);
      int ch = (kh * 4 + (l >> 4)) ^ (prow & 7);
      bf16x8 pa = *(const bf16x8*)&Ps[prow * 64 + ch * 8];
#pragma unroll
      for (int ds = 0; ds < 4; ++ds) {
        int vrow = ds * 16 + (l & 15);
        int vch = (kh * 4 + (l >> 4)) ^ (vrow & 7);
        bf16x8 vb = *(const bf16x8*)&Vts[vrow * 64 + vch * 8];
        o[ds] = MFMA(pa, vb, o[ds]);
      }
    }
  }

  // epilogue: ctx[b, q, h*64+d] = o / l   (bf16)
  const int b_ = bh / H_, h = bh - b_ * H_;
#pragma unroll
  for (int g = 0; g < 4; ++g) {
    const int q = q0 + w * 16 + ((l >> 4) << 2) + g;
    const float inv = 1.0f / l_r[g];
#pragma unroll
    for (int ds = 0; ds < 4; ++ds)
      ctx[((size_t)(b_ * S_ + q)) * 768 + h * 64 + ds * 16 + (l & 15)] =
          f2bf(o[ds][g] * inv);
  }
}

// ---------------------------------------------------------------------------
extern "C" void kernel_launch(void* const* d_in, const int* in_sizes, int n_in,
                              void* d_out, int out_size, void* d_ws,
                              size_t ws_size, hipStream_t stream) {
  const float* x = (const float*)d_in[0];
  const float* Wq = (const float*)d_in[1];
  const float* bq = (const float*)d_in[2];
  const float* Wk = (const float*)d_in[3];
  const float* bk = (const float*)d_in[4];
  const float* Wv = (const float*)d_in[5];
  const float* bv = (const float*)d_in[6];
  const float* Wo = (const float*)d_in[7];
  const float* bo = (const float*)d_in[8];

  char* p = (char*)d_ws;
  float2* trig = (float2*)p;          p += (size_t)32768 * sizeof(float2);
  u16* xb = (u16*)p;                  p += (size_t)3145728 * 2;
  u16* wqb = (u16*)p;                 p += (size_t)589824 * 2;
  u16* wkb = (u16*)p;                 p += (size_t)589824 * 2;
  u16* wvb = (u16*)p;                 p += (size_t)589824 * 2;
  u16* wob = (u16*)p;                 p += (size_t)589824 * 2;
  u16* qb = (u16*)p;                  p += (size_t)3145728 * 2;
  u16* kb = (u16*)p;                  p += (size_t)3145728 * 2;
  u16* vtb = (u16*)p;                 p += (size_t)3145728 * 2;
  u16* ctxb = (u16*)p;                p += (size_t)3145728 * 2;

  cvt_all<<<5376, 256, 0, stream>>>(x, Wq, Wk, Wv, Wo, xb, wqb, wkb, wvb, wob);
  trig_kernel<<<128, 256, 0, stream>>>(trig);

  dim3 pgrid(12, 64);
  proj_mfma<1><<<pgrid, 256, 0, stream>>>(xb, wqb, bq, qb, trig);
  proj_mfma<1><<<pgrid, 256, 0, stream>>>(xb, wkb, bk, kb, trig);
  proj_mfma<3><<<pgrid, 256, 0, stream>>>(xb, wvb, bv, vtb, nullptr);

  attn_mfma<<<dim3(32, 24), 256, 0, stream>>>(qb, kb, vtb, ctxb);

  proj_mfma<0><<<pgrid, 256, 0, stream>>>(ctxb, wob, bo, d_out, nullptr);
}

// Round 13
// 222.345 us; speedup vs baseline: 1.0063x; 1.0063x over previous
//
#include <hip/hip_runtime.h>
#include <math.h>

#define S_  2048
#define D_  768
#define H_  12

typedef float f32x4 __attribute__((ext_vector_type(4)));
typedef __bf16 bf16x8 __attribute__((ext_vector_type(8)));
typedef unsigned short u16;

#define MFMA(a, b, c) __builtin_amdgcn_mfma_f32_16x16x32_bf16(a, b, c, 0, 0, 0)
#define LOG2E 1.44269504f

__device__ __forceinline__ u16 f2bf(float f) {
  union { float f; unsigned u; } c;
  c.f = f;
  unsigned r = c.u + 0x7FFFu + ((c.u >> 16) & 1u);
  return (u16)(r >> 16);
}

typedef const unsigned int __attribute__((address_space(1))) gu32;
typedef unsigned int __attribute__((address_space(3))) lu32;

// global -> LDS direct copy, 16 B per lane. LDS dest must be wave-uniform;
// HW writes lane l at dst + l*16. Global src is per-lane.
__device__ __forceinline__ void gload_lds16(const void* g, void* l) {
  __builtin_amdgcn_global_load_lds((gu32*)g, (lu32*)l, 16, 0, 0);
}

// ---------------------------------------------------------------------------
// RoPE trig table: trig[s*16 + p] = (cos, sin)(s * 10000^(-p/16))
// ---------------------------------------------------------------------------
__global__ __launch_bounds__(256) void trig_kernel(float2* __restrict__ trig) {
  int i = blockIdx.x * 256 + threadIdx.x;
  int s = i >> 4, p = i & 15;
  float inv = powf(10000.0f, -(float)p / 16.0f);
  float f = (float)s * inv;
  trig[i] = make_float2(cosf(f), sinf(f));
}

// ---------------------------------------------------------------------------
// fp32 -> bf16 conversion of x and the 4 weight matrices (one launch).
// x: 3145728 elems (786432 float4), each W: 589824 elems (147456 float4).
// ---------------------------------------------------------------------------
__global__ __launch_bounds__(256) void cvt_all(
    const float* __restrict__ x, const float* __restrict__ wq,
    const float* __restrict__ wk, const float* __restrict__ wv,
    const float* __restrict__ wo, u16* __restrict__ xb, u16* __restrict__ wqb,
    u16* __restrict__ wkb, u16* __restrict__ wvb, u16* __restrict__ wob) {
  int idx = blockIdx.x * 256 + threadIdx.x;
  const float4* src;
  u16* dst;
  int off;
  if (idx < 786432) {
    src = (const float4*)x; dst = xb; off = idx;
  } else {
    int r = idx - 786432;
    int sel = r / 147456;
    off = r - sel * 147456;
    src = (const float4*)(sel == 0 ? wq : sel == 1 ? wk : sel == 2 ? wv : wo);
    dst = sel == 0 ? wqb : sel == 1 ? wkb : sel == 2 ? wvb : wob;
  }
  float4 v = src[off];
  ushort4 h = make_ushort4(f2bf(v.x), f2bf(v.y), f2bf(v.z), f2bf(v.w));
  *(ushort4*)(dst + (size_t)off * 4) = h;
}

// ---------------------------------------------------------------------------
// bf16 MFMA projection: out[m,n] = sum_k A[m,k] * W[n,k] + bias[n]
// M=4096, N=768, K=768. 64x64 tile, 4 waves (2x2), 16x16x32 MFMA.
// MODE 0: fp32 out[m*768+n] (final projection)
// MODE 1: RoPE + bf16 scatter to [b,h,s,64]     (q, k)
// MODE 3: bf16 transposed scatter to [b,h,64,s] (v)
// ---------------------------------------------------------------------------
template <int MODE>
__global__ __launch_bounds__(256) void proj_mfma(
    const u16* __restrict__ A, const u16* __restrict__ Wb,
    const float* __restrict__ bias, void* __restrict__ dst,
    const float2* __restrict__ trig) {
  __shared__ u16 As[4096];  // [64 m][64 k], XOR-swizzled 16B chunks
  __shared__ u16 Bs[4096];  // [64 n][64 k]
  const int t = threadIdx.x;
  const int l = t & 63, w = t >> 6;
  const int wr = w >> 1, wc = w & 1;
  const int n0 = blockIdx.x * 64;
  const int m0 = blockIdx.y * 64;

  const f32x4 zero = {0.f, 0.f, 0.f, 0.f};
  f32x4 acc[2][2];
#pragma unroll
  for (int i = 0; i < 2; ++i)
#pragma unroll
    for (int j = 0; j < 2; ++j) acc[i][j] = zero;

  for (int k0 = 0; k0 < 768; k0 += 64) {
    __syncthreads();  // previous iteration's frag reads complete
#pragma unroll
    for (int rnd = 0; rnd < 2; ++rnd) {
      int id = t + rnd * 256;
      int r = id >> 3, c = id & 7;
      int cs = ((c ^ (r & 7)) << 3);  // source pre-swizzle (rule #21)
      gload_lds16(A + (size_t)(m0 + r) * 768 + k0 + cs,
                  &As[(w * 64 + rnd * 256) * 8]);
      gload_lds16(Wb + (size_t)(n0 + r) * 768 + k0 + cs,
                  &Bs[(w * 64 + rnd * 256) * 8]);
    }
    __syncthreads();  // compiler drains vmcnt before barrier

    bf16x8 af[2][2], bw[2][2];
#pragma unroll
    for (int mf = 0; mf < 2; ++mf)
#pragma unroll
      for (int kh = 0; kh < 2; ++kh) {
        int row = wr * 32 + mf * 16 + (l & 15);
        int ch = (kh * 4 + (l >> 4)) ^ (row & 7);
        af[mf][kh] = *(const bf16x8*)&As[row * 64 + ch * 8];
      }
#pragma unroll
    for (int nf = 0; nf < 2; ++nf)
#pragma unroll
      for (int kh = 0; kh < 2; ++kh) {
        int row = wc * 32 + nf * 16 + (l & 15);
        int ch = (kh * 4 + (l >> 4)) ^ (row & 7);
        bw[nf][kh] = *(const bf16x8*)&Bs[row * 64 + ch * 8];
      }
#pragma unroll
    for (int kh = 0; kh < 2; ++kh)
#pragma unroll
      for (int mf = 0; mf < 2; ++mf)
#pragma unroll
        for (int nf = 0; nf < 2; ++nf)
          acc[mf][nf] = MFMA(af[mf][kh], bw[nf][kh], acc[mf][nf]);
  }

  // Epilogue. C layout: col = lane&15, row = (lane>>4)*4 + reg  [m89/m91]
  const int b_ = m0 >> 11;
  const int h = n0 >> 6;
#pragma unroll
  for (int mf = 0; mf < 2; ++mf) {
    const int rbase = m0 + wr * 32 + mf * 16 + ((l >> 4) << 2);
#pragma unroll
    for (int nf = 0; nf < 2; ++nf) {
      const int col = wc * 32 + nf * 16 + (l & 15);
      const int n = n0 + col;
      const float bia = bias[n];
      f32x4 v = acc[mf][nf];
      if (MODE == 0) {
        float* out = (float*)dst;
#pragma unroll
        for (int g = 0; g < 4; ++g)
          out[(size_t)(rbase + g) * 768 + n] = v[g] + bia;
      } else if (MODE == 1) {
        u16* o = (u16*)dst;
        const int d = col;  // n0 is 64-aligned -> d = col, h uniform
#pragma unroll
        for (int g = 0; g < 4; ++g) {
          float val = v[g] + bia;
          float partner = __shfl_xor(val, 1);  // paired d (d^1) value
          if (d < 32) {
            int s = (rbase + g) & (S_ - 1);
            float2 cs = trig[s * 16 + (d >> 1)];
            val = (d & 1) ? (val * cs.x + partner * cs.y)
                          : (val * cs.x - partner * cs.y);
          }
          o[((size_t)(b_ * H_ + h) * S_ + ((rbase + g) & (S_ - 1))) * 64 + d] =
              f2bf(val);
        }
      } else {  // MODE 3: V transposed [b,h,d,s]; 4 regs = 4 consecutive s
        u16* o = (u16*)dst;
        const int d = col;
        ushort4 pk;
        pk.x = f2bf(v[0] + bia);
        pk.y = f2bf(v[1] + bia);
        pk.z = f2bf(v[2] + bia);
        pk.w = f2bf(v[3] + bia);
        *(ushort4*)&o[((size_t)(b_ * H_ + h) * 64 + d) * S_ +
                      (rbase & (S_ - 1))] = pk;
      }
    }
  }
}

// ---------------------------------------------------------------------------
// bf16 MFMA causal flash attention. Block = (bh, 64 q-rows), 4 waves.
// ROUND-12 DELTA vs proven round-2 body (only kernel changed this round):
//  - double-buffered K/Vt LDS: stage tile t+1 before computing tile t,
//    ONE barrier per iteration (was 2); the vmcnt drain at that barrier now
//    waits on loads that had the whole compute phase in flight.
//  - defer-max (T13, THR=8): skip corr-exp + O-rescale unless row max grew.
// P tile unchanged (wave-private rows, no barrier).
// ---------------------------------------------------------------------------
__global__ __launch_bounds__(256) void attn_mfma(
    const u16* __restrict__ qg, const u16* __restrict__ kg,
    const u16* __restrict__ vtg, u16* __restrict__ ctx) {
  __shared__ u16 Ks[2][4096];
  __shared__ u16 Vts[2][4096];
  __shared__ u16 Ps[4096];
  const int t = threadIdx.x, l = t & 63, w = t >> 6;

  // XCD-aware bijective remap (768 = 8*96), longest q-tile first (proven
  // neutral-or-better in round 11's pass).
  int orig = blockIdx.y * 32 + blockIdx.x;
  int logical = (orig & 7) * 96 + (orig >> 3);
  const int bh = logical >> 5;
  const int qt = 31 - (logical & 31);
  const int q0 = qt * 64;

  const u16* qp = qg + (size_t)bh * (S_ * 64);
  const u16* kp = kg + (size_t)bh * (S_ * 64);
  const u16* vp = vtg + (size_t)bh * (64 * S_);

// stage K/Vt tile (kt) into LDS buffer (buf); 2 gload_lds16 rounds, source
// pre-swizzled (rule #21). All address operands wave-uniform except lane part.
#define STAGE(kt_, buf_)                                                      \
  {                                                                           \
    const int k0s = (kt_)*64;                                                 \
    _Pragma("unroll") for (int rnd = 0; rnd < 2; ++rnd) {                     \
      int id = t + rnd * 256;                                                 \
      int r = id >> 3, c = id & 7;                                            \
      int cs = ((c ^ (r & 7)) << 3);                                          \
      gload_lds16(kp + (size_t)(k0s + r) * 64 + cs,                           \
                  &Ks[buf_][(w * 64 + rnd * 256) * 8]);                       \
      gload_lds16(vp + (size_t)r * S_ + k0s + cs,                             \
                  &Vts[buf_][(w * 64 + rnd * 256) * 8]);                      \
    }                                                                         \
  }

  // Q fragments live in registers: A-layout row = l&15, k-chunk = (l>>4)*8
  bf16x8 aq[2];
  {
    const u16* qrow = qp + (size_t)(q0 + w * 16 + (l & 15)) * 64 + ((l >> 4) * 8);
    aq[0] = *(const bf16x8*)(qrow);
    aq[1] = *(const bf16x8*)(qrow + 32);
  }

  const f32x4 zero = {0.f, 0.f, 0.f, 0.f};
  f32x4 o[4];
  float m_r[4], l_r[4];
#pragma unroll
  for (int i = 0; i < 4; ++i) {
    o[i] = zero;
    m_r[i] = -3.0e38f;
    l_r[i] = 0.f;
  }

  STAGE(0, 0);
  __syncthreads();  // tile 0 resident

  for (int kt = 0; kt <= qt; ++kt) {
    const int k0 = kt * 64;
    const int cur = kt & 1;
    if (kt < qt) STAGE(kt + 1, cur ^ 1);  // prefetch flies under compute

    // S = Q K^T : D[q][kcol], 4 k-subtiles of 16
    f32x4 sacc[4];
#pragma unroll
    for (int ks = 0; ks < 4; ++ks) sacc[ks] = zero;
#pragma unroll
    for (int ks = 0; ks < 4; ++ks)
#pragma unroll
      for (int kh = 0; kh < 2; ++kh) {
        int row = ks * 16 + (l & 15);
        int ch = (kh * 4 + (l >> 4)) ^ (row & 7);
        bf16x8 bk = *(const bf16x8*)&Ks[cur][row * 64 + ch * 8];
        sacc[ks] = MFMA(aq[kh], bk, sacc[ks]);
      }

    // online softmax, rows spread over 16-lane groups; defer-max (T13)
    const int prow_b = w * 16 + ((l >> 4) << 2);
    const int qrow_b = q0 + prow_b;
#pragma unroll
    for (int g = 0; g < 4; ++g) {
      const int qrow = qrow_b + g;
      float sv[4];
#pragma unroll
      for (int ks = 0; ks < 4; ++ks) {
        int kcol = k0 + ks * 16 + (l & 15);
        float xv = sacc[ks][g] * 0.125f;
        if (kcol > qrow) xv = -3.0e38f;  // causal mask
        sv[ks] = xv;
      }
      float mx = fmaxf(fmaxf(sv[0], sv[1]), fmaxf(sv[2], sv[3]));
#pragma unroll
      for (int off = 1; off < 16; off <<= 1)
        mx = fmaxf(mx, __shfl_xor(mx, off));
      float c = 1.f;
      if (!__all(mx <= m_r[g] + 8.f)) {  // row max grew: rescale O
        float mnew = fmaxf(m_r[g], mx);
        c = __expf(m_r[g] - mnew);  // first tile: exp(-inf)=0
        m_r[g] = mnew;
#pragma unroll
        for (int ds = 0; ds < 4; ++ds) o[ds][g] *= c;
      }
      const float mm = m_r[g];
      float rs = 0.f;
      const int prow = prow_b + g;
      const int swz = (prow & 7) << 4;
#pragma unroll
      for (int ks = 0; ks < 4; ++ks) {
        float p = __expf(sv[ks] - mm);  // bounded by e^8 under defer
        rs += p;
        int byt = (ks * 32 + ((l & 15) * 2)) ^ swz;
        Ps[prow * 64 + (byt >> 1)] = f2bf(p);  // wave-private rows: no barrier
      }
#pragma unroll
      for (int off = 1; off < 16; off <<= 1) rs += __shfl_xor(rs, off);
      l_r[g] = l_r[g] * c + rs;
    }

    // O += P V : A = P[q][k] (LDS, own wave's rows), B = V[k][d] via Vt rows
#pragma unroll
    for (int kh = 0; kh < 2; ++kh) {
      int prow = w * 16 + (l & 15);
      int ch = (kh * 4 + (l >> 4)) ^ (prow & 7);
      bf16x8 pa = *(const bf16x8*)&Ps[prow * 64 + ch * 8];
#pragma unroll
      for (int ds = 0; ds < 4; ++ds) {
        int vrow = ds * 16 + (l & 15);
        int vch = (kh * 4 + (l >> 4)) ^ (vrow & 7);
        bf16x8 vb = *(const bf16x8*)&Vts[cur][vrow * 64 + vch * 8];
        o[ds] = MFMA(pa, vb, o[ds]);
      }
    }

    // one barrier/iter: (a) all waves done with buf[cur] before kt+1's STAGE
    // overwrites it; (b) drains the prefetch into buf[cur^1] (had full
    // compute phase in flight).
    __syncthreads();
  }
#undef STAGE

  // epilogue: ctx[b, q, h*64+d] = o / l   (bf16)
  const int b_ = bh / H_, h = bh - b_ * H_;
#pragma unroll
  for (int g = 0; g < 4; ++g) {
    const int q = q0 + w * 16 + ((l >> 4) << 2) + g;
    const float inv = 1.0f / l_r[g];
#pragma unroll
    for (int ds = 0; ds < 4; ++ds)
      ctx[((size_t)(b_ * S_ + q)) * 768 + h * 64 + ds * 16 + (l & 15)] =
          f2bf(o[ds][g] * inv);
  }
}

// ---------------------------------------------------------------------------
extern "C" void kernel_launch(void* const* d_in, const int* in_sizes, int n_in,
                              void* d_out, int out_size, void* d_ws,
                              size_t ws_size, hipStream_t stream) {
  const float* x = (const float*)d_in[0];
  const float* Wq = (const float*)d_in[1];
  const float* bq = (const float*)d_in[2];
  const float* Wk = (const float*)d_in[3];
  const float* bk = (const float*)d_in[4];
  const float* Wv = (const float*)d_in[5];
  const float* bv = (const float*)d_in[6];
  const float* Wo = (const float*)d_in[7];
  const float* bo = (const float*)d_in[8];

  char* p = (char*)d_ws;
  float2* trig = (float2*)p;          p += (size_t)32768 * sizeof(float2);
  u16* xb = (u16*)p;                  p += (size_t)3145728 * 2;
  u16* wqb = (u16*)p;                 p += (size_t)589824 * 2;
  u16* wkb = (u16*)p;                 p += (size_t)589824 * 2;
  u16* wvb = (u16*)p;                 p += (size_t)589824 * 2;
  u16* wob = (u16*)p;                 p += (size_t)589824 * 2;
  u16* qb = (u16*)p;                  p += (size_t)3145728 * 2;
  u16* kb = (u16*)p;                  p += (size_t)3145728 * 2;
  u16* vtb = (u16*)p;                 p += (size_t)3145728 * 2;
  u16* ctxb = (u16*)p;                p += (size_t)3145728 * 2;

  cvt_all<<<5376, 256, 0, stream>>>(x, Wq, Wk, Wv, Wo, xb, wqb, wkb, wvb, wob);
  trig_kernel<<<128, 256, 0, stream>>>(trig);

  dim3 pgrid(12, 64);
  proj_mfma<1><<<pgrid, 256, 0, stream>>>(xb, wqb, bq, qb, trig);
  proj_mfma<1><<<pgrid, 256, 0, stream>>>(xb, wkb, bk, kb, trig);
  proj_mfma<3><<<pgrid, 256, 0, stream>>>(xb, wvb, bv, vtb, nullptr);

  attn_mfma<<<dim3(32, 24), 256, 0, stream>>>(qb, kb, vtb, ctxb);

  proj_mfma<0><<<pgrid, 256, 0, stream>>>(ctxb, wob, bo, d_out, nullptr);
}